// Round 1
// baseline (373.398 us; speedup 1.0000x reference)
//
#include <hip/hip_runtime.h>
#include <cstddef>

#define BH   16
#define LSEQ 4096
#define DK   128
#define DV   128
#define C    32
#define NCH  128
#define DVB  16      // dv per scan block
#define NDVB 8
#define PP   136     // prep row-plane pitch (shorts)
#define PC   40      // pitch for [*][32] col planes (kT/vT/T/uT)
#define PS   136     // ST pitch
#define AP   33      // fp32 pitch for 32x32 A

#define NPLANE (2048u * 4096u)   // shorts per [chunk][32][128] plane array
#define NPLAT  (2048u * 1024u)   // shorts per [chunk][32][32] plane array

typedef __attribute__((ext_vector_type(4))) float f32x4;
typedef __attribute__((ext_vector_type(8))) short short8;
typedef __attribute__((ext_vector_type(4))) short s16x4;

// split-bf16: x ~= hi + lo, each bf16 rne. Returns (hi<<16)|lo.
__device__ inline unsigned split_bf16(float x) {
    unsigned u = __builtin_bit_cast(unsigned, x);
    unsigned r = u + 0x7fffu + ((u >> 16) & 1u);
    unsigned h = r >> 16;
    float hf = __builtin_bit_cast(float, r & 0xffff0000u);
    float res = x - hf;
    unsigned u2 = __builtin_bit_cast(unsigned, res);
    unsigned r2 = u2 + 0x7fffu + ((u2 >> 16) & 1u);
    return (h << 16) | (r2 >> 16);
}
__device__ inline short hi_bf16(float x) {
    unsigned u = __builtin_bit_cast(unsigned, x);
    return (short)((u + 0x7fffu + ((u >> 16) & 1u)) >> 16);
}
__device__ inline short trunc_bf16(float x) {   // x already exactly bf16
    return (short)(__builtin_bit_cast(unsigned, x) >> 16);
}

// classic pitched frag load: lane holds P[row0+(lane&15)][k0 + (lane>>4)*8 + j]
__device__ inline short8 fld(const short* P, int row0, int pitch, int k0, int lane) {
    return *(const short8*)(P + (row0 + (lane & 15)) * pitch + k0 + ((lane >> 4) << 3));
}
// swizzled pitch-128 plane frag load ([32][128], chunk c XOR row&7)
__device__ inline short8 fldz128(const short* P, int row0, int ks, int lane) {
    int row = row0 + (lane & 15);
    int c = ks * 4 + (lane >> 4);
    return *(const short8*)(P + row * 128 + ((c ^ (row & 7)) << 3));
}
// swizzled pitch-32 plane frag load ([*][32], chunk c XOR row&3), K=32
__device__ inline short8 fldz32(const short* P, int row0, int lane) {
    int row = row0 + (lane & 15);
    int c = lane >> 4;
    return *(const short8*)(P + row * 32 + ((c ^ (row & 3)) << 3));
}
__device__ inline f32x4 mf(short8 a, short8 b, f32x4 c) {
    return __builtin_amdgcn_mfma_f32_16x16x32_bf16(a, b, c, 0, 0, 0);
}
__device__ inline void build_ifrags(int lane, short8& Iev, short8& Iod) {
    int n = lane & 15, q = lane >> 4;
#pragma unroll
    for (int j = 0; j < 8; ++j) {
        Iev[j] = (q * 8 + j == n)      ? (short)0x3F80 : (short)0;
        Iod[j] = (q * 8 + j == n + 16) ? (short)0x3F80 : (short)0;
    }
}
// global swizzled stores (8B), matching the fldz layouts
__device__ inline void store8_z128(short* Pg, int row, int col0, s16x4 v) {
    int c = col0 >> 3;
    *(s16x4*)(Pg + row * 128 + ((c ^ (row & 7)) << 3) + (col0 & 7)) = v;
}
__device__ inline void store8_z32(short* Pg, int row, int col0, s16x4 v) {
    int c = col0 >> 3;
    *(s16x4*)(Pg + row * 32 + ((c ^ (row & 3)) << 3) + (col0 & 7)) = v;
}
// async global->LDS, 1KB per wave-call (lane i -> ldsbase + i*16)
__device__ inline void dma1k(const short* g, short* l, int lane) {
    __builtin_amdgcn_global_load_lds(
        (const __attribute__((address_space(1))) unsigned int*)(g + lane * 8),
        (__attribute__((address_space(3))) unsigned int*)l, 16, 0, 0);
}

// ---------------------------------------------------------------------------
// Kernel 1: per-chunk precompute. Outputs scan-ready swizzled planes:
//   QH (q l2norm, hi), WH/WL (w split), KTH/KTL (k^T split), ATH/ATL (masked
//   attn = qn@kn^T, split), Uws (fp32).
// ---------------------------------------------------------------------------
__global__ __launch_bounds__(256) void k_prep(const float* __restrict__ Q,
                                              const float* __restrict__ K,
                                              const float* __restrict__ V,
                                              const float* __restrict__ Beta,
                                              short* __restrict__ QHg,
                                              short* __restrict__ WHg,
                                              short* __restrict__ WLg,
                                              short* __restrict__ KTHg,
                                              short* __restrict__ KTLg,
                                              short* __restrict__ ATHg,
                                              short* __restrict__ ATLg,
                                              float* __restrict__ Uws) {
    __shared__ short knh[C * PP], knl[C * PP], vh[C * PP], vl[C * PP], qh[C * PP];
    __shared__ short knTh[DK * PC], knTl[DK * PC], vTh[DK * PC], vTl[DK * PC];
    __shared__ short Th[C * PC], Tl[C * PC];
    __shared__ float A[C * AP];
    __shared__ float sbeta[C];

    const int t = threadIdx.x, lane = t & 63, wv = t >> 6;
    const int quad = (t >> 4) & 3, l15 = t & 15;
    const int g = blockIdx.x;                       // bh*128 + cid
    const size_t base = (size_t)g * (C * DK);
    short8 Iev, Iod;
    build_ifrags(lane, Iev, Iod);

    if (t < C) sbeta[t] = Beta[(size_t)(g >> 7) * LSEQ + (size_t)(g & 127) * C + t];

    // ---- P0: load K,V,Q; norms; write row planes + QH global ----
    const int sr = t >> 3, sc = (t & 7) * 16;
    f32x4 kk[4], vv[4], qq[4];
#pragma unroll
    for (int g4 = 0; g4 < 4; ++g4) {
        kk[g4] = *(const f32x4*)(K + base + 16 * t + 4 * g4);
        vv[g4] = *(const f32x4*)(V + base + 16 * t + 4 * g4);
        qq[g4] = *(const f32x4*)(Q + base + 16 * t + 4 * g4);
    }
    float ssk = 0.f, ssq = 0.f;
#pragma unroll
    for (int g4 = 0; g4 < 4; ++g4) {
#pragma unroll
        for (int e = 0; e < 4; ++e) {
            ssk += kk[g4][e] * kk[g4][e];
            ssq += qq[g4][e] * qq[g4][e];
        }
    }
    ssk += __shfl_xor(ssk, 1); ssk += __shfl_xor(ssk, 2); ssk += __shfl_xor(ssk, 4);
    ssq += __shfl_xor(ssq, 1); ssq += __shfl_xor(ssq, 2); ssq += __shfl_xor(ssq, 4);
    const float rk = rsqrtf(ssk + 1e-6f), rq = rsqrtf(ssq + 1e-6f);
#pragma unroll
    for (int half = 0; half < 2; ++half) {
        short8 h8, l8;
#pragma unroll
        for (int e = 0; e < 8; ++e) {
            unsigned p = split_bf16(kk[2 * half + (e >> 2)][e & 3] * rk);
            h8[e] = (short)(p >> 16); l8[e] = (short)(p & 0xffffu);
        }
        *(short8*)(knh + sr * PP + sc + 8 * half) = h8;
        *(short8*)(knl + sr * PP + sc + 8 * half) = l8;
#pragma unroll
        for (int e = 0; e < 8; ++e) {
            unsigned p = split_bf16(vv[2 * half + (e >> 2)][e & 3]);
            h8[e] = (short)(p >> 16); l8[e] = (short)(p & 0xffffu);
        }
        *(short8*)(vh + sr * PP + sc + 8 * half) = h8;
        *(short8*)(vl + sr * PP + sc + 8 * half) = l8;
        short8 q8;
#pragma unroll
        for (int e = 0; e < 8; ++e) q8[e] = hi_bf16(qq[2 * half + (e >> 2)][e & 3] * rq);
        *(short8*)(qh + sr * PP + sc + 8 * half) = q8;
        int c = (sc >> 3) + half;
        *(short8*)(QHg + (size_t)g * 4096 + sr * 128 + ((c ^ (sr & 7)) << 3)) = q8;
    }
    __syncthreads();

    // ---- P1: G tiles -> A (strict lower, -beta scaled); attn tiles -> ATg ----
    if (wv < 3) {
        const int a0 = (wv == 0) ? 0 : 16;      // m rows (ci for attn)
        const int b0 = (wv == 2) ? 16 : 0;      // n rows (cj for attn)
        f32x4 acc = {0.f, 0.f, 0.f, 0.f};
#pragma unroll
        for (int ks = 0; ks < 4; ++ks) {
            short8 ah = fld(knh, a0, PP, ks * 32, lane);
            short8 al = fld(knl, a0, PP, ks * 32, lane);
            short8 bh_ = fld(knh, b0, PP, ks * 32, lane);
            short8 bl_ = fld(knl, b0, PP, ks * 32, lane);
            acc = mf(ah, bh_, mf(ah, bl_, mf(al, bh_, acc)));
        }
#pragma unroll
        for (int r = 0; r < 4; ++r) {
            int row = a0 + quad * 4 + r, col = b0 + l15;
            A[row * AP + col] = (row > col) ? -sbeta[row] * acc[r] : 0.f;
        }
        // attn tile: A-op = kn rows cj (m=cj), B-op = qh rows ci (n=ci)
        f32x4 at = {0.f, 0.f, 0.f, 0.f};
#pragma unroll
        for (int ks = 0; ks < 4; ++ks) {
            short8 kh_ = fld(knh, b0, PP, ks * 32, lane);
            short8 kl_ = fld(knl, b0, PP, ks * 32, lane);
            short8 qf = fld(qh, a0, PP, ks * 32, lane);
            at = mf(kh_, qf, mf(kl_, qf, at));
        }
        s16x4 h4, l4;
#pragma unroll
        for (int r = 0; r < 4; ++r) {
            int cj = b0 + quad * 4 + r, ci = a0 + l15;
            float v = (cj <= ci) ? at[r] : 0.f;
            unsigned p = split_bf16(v);
            h4[r] = (short)(p >> 16); l4[r] = (short)(p & 0xffffu);
        }
        store8_z32(ATHg + (size_t)g * 1024, a0 + l15, b0 + quad * 4, h4);
        store8_z32(ATLg + (size_t)g * 1024, a0 + l15, b0 + quad * 4, l4);
    } else {
        // zero the (rows 0-15, cols 16-31) upper tile of A and attn
#pragma unroll
        for (int r = 0; r < 4; ++r) A[l15 * AP + 16 + quad * 4 + r] = 0.f;
        s16x4 z = {0, 0, 0, 0};
        store8_z32(ATHg + (size_t)g * 1024, l15, 16 + quad * 4, z);
        store8_z32(ATLg + (size_t)g * 1024, l15, 16 + quad * 4, z);
    }
    __syncthreads();

    // ---- P2: transposes (LDS + KT global) on wv0-2; substitution on wv3 ----
    auto tplane = [&](const short* src, short* dst, short* gdst) {
#pragma unroll
        for (int c0 = 0; c0 <= 16; c0 += 16) {
#pragma unroll
            for (int ks = 0; ks < 4; ++ks) {
                short8 fr = fld(src, c0, PP, ks * 32, lane);
                f32x4 z = {0.f, 0.f, 0.f, 0.f};
                f32x4 cA = mf(fr, Iev, z);
                f32x4 cB = mf(fr, Iod, z);
                s16x4 sA, sB;
#pragma unroll
                for (int r = 0; r < 4; ++r) { sA[r] = trunc_bf16(cA[r]); sB[r] = trunc_bf16(cB[r]); }
                *(s16x4*)(dst + (ks * 32 + l15) * PC + c0 + quad * 4) = sA;
                *(s16x4*)(dst + (ks * 32 + 16 + l15) * PC + c0 + quad * 4) = sB;
                if (gdst) {
                    store8_z32(gdst, ks * 32 + l15, c0 + quad * 4, sA);
                    store8_z32(gdst, ks * 32 + 16 + l15, c0 + quad * 4, sB);
                }
            }
        }
    };
    if (wv == 0) {
        tplane(knh, knTh, KTHg + (size_t)g * 4096);
        tplane(vl, vTl, nullptr);
    } else if (wv == 1) {
        tplane(knl, knTl, KTLg + (size_t)g * 4096);
    } else if (wv == 2) {
        tplane(vh, vTh, nullptr);
    } else if (lane < C) {
        const int j = lane;       // forward substitution (upper of A is zero)
        for (int i = 1; i < C; ++i) {
            float upd = 0.f;
            for (int kk2 = 1; kk2 < i; ++kk2) upd += A[i * AP + kk2] * A[kk2 * AP + j];
            if (j < i) A[i * AP + j] += upd;
        }
    }
    __syncthreads();

    // ---- P3: T' = (A + I) * diag(beta) -> Th/Tl ----
    {
        int tr = t >> 3, tc = (t & 7) * 4;
        s16x4 h4, l4;
#pragma unroll
        for (int e = 0; e < 4; ++e) {
            int j = tc + e;
            float val = ((tr == j) ? 1.f : (tr > j ? A[tr * AP + j] : 0.f)) * sbeta[j];
            unsigned p = split_bf16(val);
            h4[e] = (short)(p >> 16); l4[e] = (short)(p & 0xffffu);
        }
        *(s16x4*)(Th + tr * PC + tc) = h4;
        *(s16x4*)(Tl + tr * PC + tc) = l4;
    }
    __syncthreads();

    // ---- P4: u = T'@v (fp32 -> Uws), w = T'@kn (split -> WH/WL planes) ----
    {
        const int ci0 = (wv & 1) * 16;
        short8 bTh = fld(Th, ci0, PC, 0, lane);
        short8 bTl = fld(Tl, ci0, PC, 0, lane);
        if (wv < 2) {
#pragma unroll
            for (int tt = 0; tt < 8; ++tt) {
                short8 ah = fld(vTh, tt * 16, PC, 0, lane);
                short8 al = fld(vTl, tt * 16, PC, 0, lane);
                f32x4 z = {0.f, 0.f, 0.f, 0.f};
                f32x4 acc = mf(ah, bTh, mf(ah, bTl, mf(al, bTh, z)));
                *(f32x4*)(Uws + (size_t)g * 4096 + (size_t)(ci0 + l15) * DK + tt * 16 + quad * 4) = acc;
            }
        } else {
#pragma unroll
            for (int tt = 0; tt < 8; ++tt) {
                short8 ah = fld(knTh, tt * 16, PC, 0, lane);
                short8 al = fld(knTl, tt * 16, PC, 0, lane);
                f32x4 z = {0.f, 0.f, 0.f, 0.f};
                f32x4 acc = mf(ah, bTh, mf(ah, bTl, mf(al, bTh, z)));
                s16x4 h4, l4;
#pragma unroll
                for (int r = 0; r < 4; ++r) {
                    unsigned p = split_bf16(acc[r]);
                    h4[r] = (short)(p >> 16); l4[r] = (short)(p & 0xffffu);
                }
                store8_z128(WHg + (size_t)g * 4096, ci0 + l15, tt * 16 + quad * 4, h4);
                store8_z128(WLg + (size_t)g * 4096, ci0 + l15, tt * 16 + quad * 4, l4);
            }
        }
    }
}

// ---------------------------------------------------------------------------
// Kernel 2: sequential chunk scan. 128 blocks = 8 dv-slices x 16 bh, 8 waves.
// Software-pipelined: DMA for chunk cid+1 issued BEFORE stage 1 of chunk cid;
// raw barriers with counted waits keep the DMA in flight across the mid
// barrier (lgkmcnt-only) and drain it at the end barrier, where ~a full
// iteration of compute has covered its latency. Out store for chunk cid is
// deferred to the top of iteration cid+1 so its ack retires ahead of the DMA.
// ---------------------------------------------------------------------------
__global__ __launch_bounds__(512, 1) void k_scan(const short* __restrict__ QHg,
                                                 const short* __restrict__ WHg,
                                                 const short* __restrict__ WLg,
                                                 const short* __restrict__ KTHg,
                                                 const short* __restrict__ KTLg,
                                                 const short* __restrict__ ATHg,
                                                 const short* __restrict__ ATLg,
                                                 const float* __restrict__ Uws,
                                                 float* __restrict__ Out,
                                                 float* __restrict__ Sout) {
    __shared__ short bQ[2][4096], bWH[2][4096], bWL[2][4096], bKTH[2][4096], bKTL[2][4096];
    __shared__ short bATH[2][1024], bATL[2][1024];
    __shared__ short STh[DVB * PS], STl[DVB * PS];
    __shared__ short uTh[DVB * PC], uTl[DVB * PC];

    const int t = threadIdx.x, lane = t & 63, wv = t >> 6;
    const int quad = (t >> 4) & 3, l15 = t & 15;
    const int db = blockIdx.x >> 4, bhi = blockIdx.x & 15;
    const int vcol = db * DVB;
    const int r0 = (wv & 1) * 16;          // ci tile for wv0/1
    const int dk0 = wv * 16;               // S dk-tile per wave
    const size_t gb = (size_t)bhi * NCH;   // chunk index base

    f32x4 accS = {0.f, 0.f, 0.f, 0.f};

    auto dma_chunk = [&](int cc, int s) {
        const size_t go = (gb + cc) * 4096;
        dma1k(QHg + go + wv * 512, &bQ[s][wv * 512], lane);
        dma1k(WHg + go + wv * 512, &bWH[s][wv * 512], lane);
        dma1k(WLg + go + wv * 512, &bWL[s][wv * 512], lane);
        dma1k(KTHg + go + wv * 512, &bKTH[s][wv * 512], lane);
        dma1k(KTLg + go + wv * 512, &bKTL[s][wv * 512], lane);
        if (wv < 4) {
            const size_t ga = (gb + cc) * 1024 + (size_t)(wv & 1) * 512;
            if (wv < 2) dma1k(ATHg + ga, &bATH[s][(wv & 1) * 512], lane);
            else        dma1k(ATLg + ga, &bATL[s][(wv & 1) * 512], lane);
        }
    };
    auto pref_u = [&](int cc, f32x4& pn) {
        if (wv < 2) {
            const size_t ub = (gb + cc) * 4096;
#pragma unroll
            for (int r = 0; r < 4; ++r)
                pn[r] = Uws[ub + (size_t)(r0 + quad * 4 + r) * DK + vcol + l15];
        }
    };

    for (int e = t; e < DVB * PS; e += 512) { STh[e] = 0; STl[e] = 0; }
    f32x4 puA = {0.f, 0.f, 0.f, 0.f}, puB = {0.f, 0.f, 0.f, 0.f};
    f32x4 ocp = {0.f, 0.f, 0.f, 0.f};
    dma_chunk(0, 0);
    pref_u(0, puA);
    __syncthreads();   // full drain: DMA(0) + pu(0) resident

    // one scan iteration; cur is compile-time-fixed by the unroll-by-2 below,
    // pu double-buffer passed as distinct named f32x4 regs (no runtime idx).
    auto body = [&](int cid, int cur, f32x4& puC, f32x4& puN) {
        // ---- top: deferred Out store (chunk cid-1), then next-chunk prefetch ----
        if (wv < 2 && cid > 0) {
            const size_t ob = ((size_t)bhi * LSEQ + (size_t)(cid - 1) * C) * DK;
            *(f32x4*)(Out + ob + (size_t)(r0 + l15) * DK + vcol + quad * 4) = ocp;
        }
        if (cid + 1 < NCH) {
            dma_chunk(cid + 1, cur ^ 1);
            pref_u(cid + 1, puN);
        }

        // ---- stage 1: u' = u - w@S and o1 = q@S (wv0/1 only) ----
        f32x4 oc = {0.f, 0.f, 0.f, 0.f};
        if (wv < 2) {
            f32x4 u0 = {-puC[0], -puC[1], -puC[2], -puC[3]};
            f32x4 u1 = {0.f, 0.f, 0.f, 0.f}, u2 = {0.f, 0.f, 0.f, 0.f};
            f32x4 o1 = {0.f, 0.f, 0.f, 0.f};
#pragma unroll
            for (int ks = 0; ks < 4; ++ks) {
                short8 wh_ = fldz128(bWH[cur], r0, ks, lane);
                short8 wl_ = fldz128(bWL[cur], r0, ks, lane);
                short8 sh_ = fld(STh, 0, PS, ks * 32, lane);
                short8 sl_ = fld(STl, 0, PS, ks * 32, lane);
                short8 qf = fldz128(bQ[cur], r0, ks, lane);
                u0 = mf(wh_, sh_, u0);          // independent chains
                u1 = mf(wh_, sl_, u1);
                u2 = mf(wl_, sh_, u2);
                oc = mf(sh_, qf, oc);           // o^T[dv][ci]
                o1 = mf(sl_, qf, o1);
            }
            oc += o1;
            f32x4 us = u0 + u1 + u2;            // = w@S - u
            s16x4 h4, l4;
#pragma unroll
            for (int r = 0; r < 4; ++r) {
                unsigned p = split_bf16(-us[r]);
                h4[r] = (short)(p >> 16); l4[r] = (short)(p & 0xffffu);
            }
            *(s16x4*)(uTh + l15 * PC + r0 + quad * 4) = h4;   // u'^T[dv][c]
            *(s16x4*)(uTl + l15 * PC + r0 + quad * 4) = l4;
        }
        // mid barrier: LDS (uT) visibility only — DMA stays in flight (vmcnt untouched)
        asm volatile("s_waitcnt lgkmcnt(0)\n\ts_barrier" ::: "memory");

        // ---- stage 2: o finish + S accumulate + S replanes ----
        short8 buh = fld(uTh, 0, PC, 0, lane);
        short8 bul = fld(uTl, 0, PC, 0, lane);
        if (wv < 2) {
            short8 bah = fldz32(bATH[cur], r0, lane);
            short8 bal = fldz32(bATL[cur], r0, lane);
            oc = mf(buh, bah, mf(buh, bal, mf(bul, bah, oc)));
            ocp = oc;                            // stored at top of next iteration
        }
        {
            short8 kth = fldz32(bKTH[cur], dk0, lane);
            short8 ktl = fldz32(bKTL[cur], dk0, lane);
            f32x4 z = {0.f, 0.f, 0.f, 0.f};
            f32x4 tband = mf(kth, bul, mf(ktl, buh, z));
            accS = mf(kth, buh, accS);
            accS += tband;
            s16x4 h4, l4;
#pragma unroll
            for (int r = 0; r < 4; ++r) {
                unsigned p = split_bf16(accS[r]);
                h4[r] = (short)(p >> 16); l4[r] = (short)(p & 0xffffu);
            }
            *(s16x4*)(STh + l15 * PS + dk0 + quad * 4) = h4;   // S^T[dv][dk]
            *(s16x4*)(STl + l15 * PS + dk0 + quad * 4) = l4;
        }
        // end barrier: own DMA + pu drained (issued a full iteration ago),
        // S/uT LDS writes visible; then all waves may read buffer cur^1.
        asm volatile("s_waitcnt vmcnt(0) lgkmcnt(0)\n\ts_barrier" ::: "memory");
    };

    for (int cp = 0; cp < NCH / 2; ++cp) {
        body(2 * cp,     0, puA, puB);
        body(2 * cp + 1, 1, puB, puA);
    }
    // flush last chunk's output tile
    if (wv < 2) {
        const size_t ob = ((size_t)bhi * LSEQ + (size_t)(NCH - 1) * C) * DK;
        *(f32x4*)(Out + ob + (size_t)(r0 + l15) * DK + vcol + quad * 4) = ocp;
    }

    // final state: Sout[bh][dk][dv]
#pragma unroll
    for (int r = 0; r < 4; ++r)
        Sout[(size_t)bhi * DK * DV + (size_t)(dk0 + quad * 4 + r) * DV + vcol + l15] = accS[r];
}

extern "C" void kernel_launch(void* const* d_in, const int* in_sizes, int n_in,
                              void* d_out, int out_size, void* d_ws, size_t ws_size,
                              hipStream_t stream) {
    const float* Q    = (const float*)d_in[0];
    const float* K    = (const float*)d_in[1];
    const float* V    = (const float*)d_in[2];
    const float* Beta = (const float*)d_in[3];

    float* Out  = (float*)d_out;
    float* Sout = Out + (size_t)BH * LSEQ * DV;

    short* QHg  = (short*)d_ws;
    short* WHg  = QHg + NPLANE;
    short* WLg  = WHg + NPLANE;
    short* KTHg = WLg + NPLANE;
    short* KTLg = KTHg + NPLANE;
    short* ATHg = KTLg + NPLANE;
    short* ATLg = ATHg + NPLAT;
    float* Uws  = (float*)(ATLg + NPLAT);   // total ws: 120 MiB

    hipLaunchKernelGGL(k_prep, dim3(BH * NCH), dim3(256), 0, stream,
                       Q, K, V, Beta, QHg, WHg, WLg, KTHg, KTLg, ATHg, ATLg, Uws);
    hipLaunchKernelGGL(k_scan, dim3(BH * NDVB), dim3(512), 0, stream,
                       QHg, WHg, WLg, KTHg, KTLg, ATHg, ATLg, Uws, Out, Sout);
}

// Round 2
// 339.400 us; speedup vs baseline: 1.1002x; 1.1002x over previous
//
#include <hip/hip_runtime.h>
#include <cstddef>

#define BH   16
#define LSEQ 4096
#define DK   128
#define DV   128
#define C    32
#define NCH  128
#define DVB  16      // dv per scan block
#define NDVB 8
#define PP   136     // prep row-plane pitch (shorts)
#define PC   40      // pitch for [*][32] col planes (kT/vT/T/uT)
#define PS   136     // ST pitch
#define AP   33      // fp32 pitch for 32x32 A

// per-(bh,chunk) contiguous record in workspace (shorts):
// [QH 4096 | WH 4096 | WL 4096 | KTH 4096 | KTL 4096 | ATH 1024 | ATL 1024]
#define RECSZ 22528
#define OQ    0
#define OWH   4096
#define OWL   8192
#define OKTH  12288
#define OKTL  16384
#define OATH  20480
#define OATL  21504

typedef __attribute__((ext_vector_type(4))) float f32x4;
typedef __attribute__((ext_vector_type(8))) short short8;
typedef __attribute__((ext_vector_type(4))) short s16x4;

// split-bf16: x ~= hi + lo, each bf16 rne. Returns (hi<<16)|lo.
__device__ inline unsigned split_bf16(float x) {
    unsigned u = __builtin_bit_cast(unsigned, x);
    unsigned r = u + 0x7fffu + ((u >> 16) & 1u);
    unsigned h = r >> 16;
    float hf = __builtin_bit_cast(float, r & 0xffff0000u);
    float res = x - hf;
    unsigned u2 = __builtin_bit_cast(unsigned, res);
    unsigned r2 = u2 + 0x7fffu + ((u2 >> 16) & 1u);
    return (h << 16) | (r2 >> 16);
}
__device__ inline short hi_bf16(float x) {
    unsigned u = __builtin_bit_cast(unsigned, x);
    return (short)((u + 0x7fffu + ((u >> 16) & 1u)) >> 16);
}
__device__ inline short trunc_bf16(float x) {   // x already exactly bf16
    return (short)(__builtin_bit_cast(unsigned, x) >> 16);
}

// classic pitched frag load: lane holds P[row0+(lane&15)][k0 + (lane>>4)*8 + j]
__device__ inline short8 fld(const short* P, int row0, int pitch, int k0, int lane) {
    return *(const short8*)(P + (row0 + (lane & 15)) * pitch + k0 + ((lane >> 4) << 3));
}
// swizzled pitch-128 plane frag load ([32][128], chunk c XOR row&7)
__device__ inline short8 fldz128(const short* P, int row0, int ks, int lane) {
    int row = row0 + (lane & 15);
    int c = ks * 4 + (lane >> 4);
    return *(const short8*)(P + row * 128 + ((c ^ (row & 7)) << 3));
}
// swizzled pitch-32 plane frag load ([*][32], chunk c XOR row&3), K=32
__device__ inline short8 fldz32(const short* P, int row0, int lane) {
    int row = row0 + (lane & 15);
    int c = lane >> 4;
    return *(const short8*)(P + row * 32 + ((c ^ (row & 3)) << 3));
}
__device__ inline f32x4 mf(short8 a, short8 b, f32x4 c) {
    return __builtin_amdgcn_mfma_f32_16x16x32_bf16(a, b, c, 0, 0, 0);
}
__device__ inline void build_ifrags(int lane, short8& Iev, short8& Iod) {
    int n = lane & 15, q = lane >> 4;
#pragma unroll
    for (int j = 0; j < 8; ++j) {
        Iev[j] = (q * 8 + j == n)      ? (short)0x3F80 : (short)0;
        Iod[j] = (q * 8 + j == n + 16) ? (short)0x3F80 : (short)0;
    }
}
// global swizzled stores (8B), matching the fldz layouts
__device__ inline void store8_z128(short* Pg, int row, int col0, s16x4 v) {
    int c = col0 >> 3;
    *(s16x4*)(Pg + row * 128 + ((c ^ (row & 7)) << 3) + (col0 & 7)) = v;
}
__device__ inline void store8_z32(short* Pg, int row, int col0, s16x4 v) {
    int c = col0 >> 3;
    *(s16x4*)(Pg + row * 32 + ((c ^ (row & 3)) << 3) + (col0 & 7)) = v;
}
// async global->LDS, 1KB per wave-call (lane i -> ldsbase + i*16)
__device__ inline void dma1k(const short* g, short* l, int lane) {
    __builtin_amdgcn_global_load_lds(
        (const __attribute__((address_space(1))) unsigned int*)(g + lane * 8),
        (__attribute__((address_space(3))) unsigned int*)l, 16, 0, 0);
}

// ---------------------------------------------------------------------------
// Kernel 1: per-chunk precompute. Writes one contiguous scan-ready record per
// (bh,chunk): QH (q l2norm, hi), WH/WL (w split), KTH/KTL (k^T split),
// ATH/ATL (masked attn split) — plus Uws (fp32, separate).
// ---------------------------------------------------------------------------
__global__ __launch_bounds__(256) void k_prep(const float* __restrict__ Q,
                                              const float* __restrict__ K,
                                              const float* __restrict__ V,
                                              const float* __restrict__ Beta,
                                              short* __restrict__ RECg,
                                              float* __restrict__ Uws) {
    __shared__ short knh[C * PP], knl[C * PP], vh[C * PP], vl[C * PP], qh[C * PP];
    __shared__ short knTh[DK * PC], knTl[DK * PC], vTh[DK * PC], vTl[DK * PC];
    __shared__ short Th[C * PC], Tl[C * PC];
    __shared__ float A[C * AP];
    __shared__ float sbeta[C];

    const int t = threadIdx.x, lane = t & 63, wv = t >> 6;
    const int quad = (t >> 4) & 3, l15 = t & 15;
    const int g = blockIdx.x;                       // bh*128 + cid
    const size_t base = (size_t)g * (C * DK);
    short* rec = RECg + (size_t)g * RECSZ;
    short8 Iev, Iod;
    build_ifrags(lane, Iev, Iod);

    if (t < C) sbeta[t] = Beta[(size_t)(g >> 7) * LSEQ + (size_t)(g & 127) * C + t];

    // ---- P0: load K,V,Q; norms; write row planes + QH record ----
    const int sr = t >> 3, sc = (t & 7) * 16;
    f32x4 kk[4], vv[4], qq[4];
#pragma unroll
    for (int g4 = 0; g4 < 4; ++g4) {
        kk[g4] = *(const f32x4*)(K + base + 16 * t + 4 * g4);
        vv[g4] = *(const f32x4*)(V + base + 16 * t + 4 * g4);
        qq[g4] = *(const f32x4*)(Q + base + 16 * t + 4 * g4);
    }
    float ssk = 0.f, ssq = 0.f;
#pragma unroll
    for (int g4 = 0; g4 < 4; ++g4) {
#pragma unroll
        for (int e = 0; e < 4; ++e) {
            ssk += kk[g4][e] * kk[g4][e];
            ssq += qq[g4][e] * qq[g4][e];
        }
    }
    ssk += __shfl_xor(ssk, 1); ssk += __shfl_xor(ssk, 2); ssk += __shfl_xor(ssk, 4);
    ssq += __shfl_xor(ssq, 1); ssq += __shfl_xor(ssq, 2); ssq += __shfl_xor(ssq, 4);
    const float rk = rsqrtf(ssk + 1e-6f), rq = rsqrtf(ssq + 1e-6f);
#pragma unroll
    for (int half = 0; half < 2; ++half) {
        short8 h8, l8;
#pragma unroll
        for (int e = 0; e < 8; ++e) {
            unsigned p = split_bf16(kk[2 * half + (e >> 2)][e & 3] * rk);
            h8[e] = (short)(p >> 16); l8[e] = (short)(p & 0xffffu);
        }
        *(short8*)(knh + sr * PP + sc + 8 * half) = h8;
        *(short8*)(knl + sr * PP + sc + 8 * half) = l8;
#pragma unroll
        for (int e = 0; e < 8; ++e) {
            unsigned p = split_bf16(vv[2 * half + (e >> 2)][e & 3]);
            h8[e] = (short)(p >> 16); l8[e] = (short)(p & 0xffffu);
        }
        *(short8*)(vh + sr * PP + sc + 8 * half) = h8;
        *(short8*)(vl + sr * PP + sc + 8 * half) = l8;
        short8 q8;
#pragma unroll
        for (int e = 0; e < 8; ++e) q8[e] = hi_bf16(qq[2 * half + (e >> 2)][e & 3] * rq);
        *(short8*)(qh + sr * PP + sc + 8 * half) = q8;
        int c = (sc >> 3) + half;
        *(short8*)(rec + OQ + sr * 128 + ((c ^ (sr & 7)) << 3)) = q8;
    }
    __syncthreads();

    // ---- P1: G tiles -> A (strict lower, -beta scaled); attn tiles -> record ----
    if (wv < 3) {
        const int a0 = (wv == 0) ? 0 : 16;      // m rows (ci for attn)
        const int b0 = (wv == 2) ? 16 : 0;      // n rows (cj for attn)
        f32x4 acc = {0.f, 0.f, 0.f, 0.f};
#pragma unroll
        for (int ks = 0; ks < 4; ++ks) {
            short8 ah = fld(knh, a0, PP, ks * 32, lane);
            short8 al = fld(knl, a0, PP, ks * 32, lane);
            short8 bh_ = fld(knh, b0, PP, ks * 32, lane);
            short8 bl_ = fld(knl, b0, PP, ks * 32, lane);
            acc = mf(ah, bh_, mf(ah, bl_, mf(al, bh_, acc)));
        }
#pragma unroll
        for (int r = 0; r < 4; ++r) {
            int row = a0 + quad * 4 + r, col = b0 + l15;
            A[row * AP + col] = (row > col) ? -sbeta[row] * acc[r] : 0.f;
        }
        // attn tile: A-op = kn rows cj (m=cj), B-op = qh rows ci (n=ci)
        f32x4 at = {0.f, 0.f, 0.f, 0.f};
#pragma unroll
        for (int ks = 0; ks < 4; ++ks) {
            short8 kh_ = fld(knh, b0, PP, ks * 32, lane);
            short8 kl_ = fld(knl, b0, PP, ks * 32, lane);
            short8 qf = fld(qh, a0, PP, ks * 32, lane);
            at = mf(kh_, qf, mf(kl_, qf, at));
        }
        s16x4 h4, l4;
#pragma unroll
        for (int r = 0; r < 4; ++r) {
            int cj = b0 + quad * 4 + r, ci = a0 + l15;
            float v = (cj <= ci) ? at[r] : 0.f;
            unsigned p = split_bf16(v);
            h4[r] = (short)(p >> 16); l4[r] = (short)(p & 0xffffu);
        }
        store8_z32(rec + OATH, a0 + l15, b0 + quad * 4, h4);
        store8_z32(rec + OATL, a0 + l15, b0 + quad * 4, l4);
    } else {
        // zero the (rows 0-15, cols 16-31) upper tile of A and attn
#pragma unroll
        for (int r = 0; r < 4; ++r) A[l15 * AP + 16 + quad * 4 + r] = 0.f;
        s16x4 z = {0, 0, 0, 0};
        store8_z32(rec + OATH, l15, 16 + quad * 4, z);
        store8_z32(rec + OATL, l15, 16 + quad * 4, z);
    }
    __syncthreads();

    // ---- P2: transposes (LDS + KT record) on wv0-2; substitution on wv3 ----
    auto tplane = [&](const short* src, short* dst, short* gdst) {
#pragma unroll
        for (int c0 = 0; c0 <= 16; c0 += 16) {
#pragma unroll
            for (int ks = 0; ks < 4; ++ks) {
                short8 fr = fld(src, c0, PP, ks * 32, lane);
                f32x4 z = {0.f, 0.f, 0.f, 0.f};
                f32x4 cA = mf(fr, Iev, z);
                f32x4 cB = mf(fr, Iod, z);
                s16x4 sA, sB;
#pragma unroll
                for (int r = 0; r < 4; ++r) { sA[r] = trunc_bf16(cA[r]); sB[r] = trunc_bf16(cB[r]); }
                *(s16x4*)(dst + (ks * 32 + l15) * PC + c0 + quad * 4) = sA;
                *(s16x4*)(dst + (ks * 32 + 16 + l15) * PC + c0 + quad * 4) = sB;
                if (gdst) {
                    store8_z32(gdst, ks * 32 + l15, c0 + quad * 4, sA);
                    store8_z32(gdst, ks * 32 + 16 + l15, c0 + quad * 4, sB);
                }
            }
        }
    };
    if (wv == 0) {
        tplane(knh, knTh, rec + OKTH);
        tplane(vl, vTl, nullptr);
    } else if (wv == 1) {
        tplane(knl, knTl, rec + OKTL);
    } else if (wv == 2) {
        tplane(vh, vTh, nullptr);
    } else if (lane < C) {
        const int j = lane;       // forward substitution (upper of A is zero)
        for (int i = 1; i < C; ++i) {
            float upd = 0.f;
            for (int kk2 = 1; kk2 < i; ++kk2) upd += A[i * AP + kk2] * A[kk2 * AP + j];
            if (j < i) A[i * AP + j] += upd;
        }
    }
    __syncthreads();

    // ---- P3: T' = (A + I) * diag(beta) -> Th/Tl ----
    {
        int tr = t >> 3, tc = (t & 7) * 4;
        s16x4 h4, l4;
#pragma unroll
        for (int e = 0; e < 4; ++e) {
            int j = tc + e;
            float val = ((tr == j) ? 1.f : (tr > j ? A[tr * AP + j] : 0.f)) * sbeta[j];
            unsigned p = split_bf16(val);
            h4[e] = (short)(p >> 16); l4[e] = (short)(p & 0xffffu);
        }
        *(s16x4*)(Th + tr * PC + tc) = h4;
        *(s16x4*)(Tl + tr * PC + tc) = l4;
    }
    __syncthreads();

    // ---- P4: u = T'@v (fp32 -> Uws), w = T'@kn (split -> record) ----
    {
        const int ci0 = (wv & 1) * 16;
        short8 bTh = fld(Th, ci0, PC, 0, lane);
        short8 bTl = fld(Tl, ci0, PC, 0, lane);
        if (wv < 2) {
#pragma unroll
            for (int tt = 0; tt < 8; ++tt) {
                short8 ah = fld(vTh, tt * 16, PC, 0, lane);
                short8 al = fld(vTl, tt * 16, PC, 0, lane);
                f32x4 z = {0.f, 0.f, 0.f, 0.f};
                f32x4 acc = mf(ah, bTh, mf(ah, bTl, mf(al, bTh, z)));
                *(f32x4*)(Uws + (size_t)g * 4096 + (size_t)(ci0 + l15) * DK + tt * 16 + quad * 4) = acc;
            }
        } else {
#pragma unroll
            for (int tt = 0; tt < 8; ++tt) {
                short8 ah = fld(knTh, tt * 16, PC, 0, lane);
                short8 al = fld(knTl, tt * 16, PC, 0, lane);
                f32x4 z = {0.f, 0.f, 0.f, 0.f};
                f32x4 acc = mf(ah, bTh, mf(ah, bTl, mf(al, bTh, z)));
                s16x4 h4, l4;
#pragma unroll
                for (int r = 0; r < 4; ++r) {
                    unsigned p = split_bf16(acc[r]);
                    h4[r] = (short)(p >> 16); l4[r] = (short)(p & 0xffffu);
                }
                store8_z128(rec + OWH, ci0 + l15, tt * 16 + quad * 4, h4);
                store8_z128(rec + OWL, ci0 + l15, tt * 16 + quad * 4, l4);
            }
        }
    }
}

// ---------------------------------------------------------------------------
// Kernel 2: sequential chunk scan. 128 blocks = 8 dv-slices x 16 bh, 8 waves.
// Wave-specialized prefetch: wv2-7 (idle in stage 1) issue ALL next-chunk DMA
// at the top of the iteration; their vmcnt(0) drain inside the mid
// __syncthreads overlaps the wait for wv0/1's stage-1 compute. wv0/1 issue no
// DMA at all (no compiler alias-waits in stage 1) and prefetch u to registers
// at the top. Both barriers are plain __syncthreads (no asm, no races).
// ---------------------------------------------------------------------------
__global__ __launch_bounds__(512, 1) void k_scan(const short* __restrict__ RECg,
                                                 const float* __restrict__ Uws,
                                                 float* __restrict__ Out,
                                                 float* __restrict__ Sout) {
    __shared__ __attribute__((aligned(16))) short bALL[2][RECSZ];
    __shared__ short STh[DVB * PS], STl[DVB * PS];
    __shared__ short uTh[DVB * PC], uTl[DVB * PC];

    const int t = threadIdx.x, lane = t & 63, wv = t >> 6;
    const int quad = (t >> 4) & 3, l15 = t & 15;
    const int db = blockIdx.x >> 4, bhi = blockIdx.x & 15;
    const int vcol = db * DVB;
    const int r0 = (wv & 1) * 16;          // ci tile for wv0/1
    const int dk0 = wv * 16;               // S dk-tile per wave
    const size_t gb = (size_t)bhi * NCH;   // chunk index base

    f32x4 accS = {0.f, 0.f, 0.f, 0.f};
    float pu[4] = {0.f, 0.f, 0.f, 0.f};

    // wv2-7 copy the whole 44KB record (44 x 1KB units, strided by 6 waves)
    auto dma_chunk = [&](int cc, int s) {
        if (wv < 2) return;
        const short* src = RECg + (size_t)(gb + cc) * RECSZ;
        short* dst = bALL[s];
#pragma unroll
        for (int k = 0; k < 8; ++k) {
            int q = (wv - 2) + 6 * k;
            if (q < 44) dma1k(src + q * 512, dst + q * 512, lane);
        }
    };
    auto pref_u = [&](int cc) {
        if (wv < 2) {
            const size_t ub = (gb + cc) * 4096;
#pragma unroll
            for (int r = 0; r < 4; ++r)
                pu[r] = Uws[ub + (size_t)(r0 + quad * 4 + r) * DK + vcol + l15];
        }
    };

    for (int e = t; e < DVB * PS; e += 512) { STh[e] = 0; STl[e] = 0; }
    dma_chunk(0, 0);
    pref_u(0);
    __syncthreads();   // drains DMA(0) + pu(0)

    for (int cid = 0; cid < NCH; ++cid) {
        const int cur = cid & 1;
        const short* pC = bALL[cur];
        f32x4 oc = {0.f, 0.f, 0.f, 0.f};

        // preload S-update operands for stage 2 (buffer `cur` is stable all
        // iteration). These reads PRECEDE any DMA issue in program order, so
        // no conservative vmcnt wait lands on them.
        short8 kth = fldz32(pC + OKTH, dk0, lane);
        short8 ktl = fldz32(pC + OKTL, dk0, lane);
        short8 bah = {}, bal = {};

        if (wv >= 2) {
            // ---- producers: issue next-chunk DMA now; mid-sync drain
            //      overlaps the barrier wait for wv0/1's stage 1 ----
            if (cid + 1 < NCH) dma_chunk(cid + 1, cur ^ 1);
        } else {
            // ---- consumers: capture u, prefetch next u, stage 1 ----
            float p0 = pu[0], p1 = pu[1], p2 = pu[2], p3 = pu[3];
            if (cid + 1 < NCH) pref_u(cid + 1);

            f32x4 u0 = {-p0, -p1, -p2, -p3};
            f32x4 u1 = {0.f, 0.f, 0.f, 0.f}, u2 = {0.f, 0.f, 0.f, 0.f};
            f32x4 o1 = {0.f, 0.f, 0.f, 0.f};
#pragma unroll
            for (int ks = 0; ks < 4; ++ks) {
                short8 wh_ = fldz128(pC + OWH, r0, ks, lane);
                short8 wl_ = fldz128(pC + OWL, r0, ks, lane);
                short8 sh_ = fld(STh, 0, PS, ks * 32, lane);
                short8 sl_ = fld(STl, 0, PS, ks * 32, lane);
                short8 qf = fldz128(pC + OQ, r0, ks, lane);
                u0 = mf(wh_, sh_, u0);          // independent chains
                u1 = mf(wh_, sl_, u1);
                u2 = mf(wl_, sh_, u2);
                oc = mf(sh_, qf, oc);           // o^T[dv][ci]
                o1 = mf(sl_, qf, o1);
            }
            oc += o1;
            f32x4 us = u0 + u1 + u2;            // = w@S - u
            s16x4 h4, l4;
#pragma unroll
            for (int r = 0; r < 4; ++r) {
                unsigned p = split_bf16(-us[r]);
                h4[r] = (short)(p >> 16); l4[r] = (short)(p & 0xffffu);
            }
            *(s16x4*)(uTh + l15 * PC + r0 + quad * 4) = h4;   // u'^T[dv][c]
            *(s16x4*)(uTl + l15 * PC + r0 + quad * 4) = l4;
            // preload attn tiles for stage 2
            bah = fldz32(pC + OATH, r0, lane);
            bal = fldz32(pC + OATL, r0, lane);
        }
        __syncthreads();   // mid: uT visible; wv2-7's DMA drain overlapped here

        // ---- stage 2: o finish + S accumulate + S replanes ----
        short8 buh = fld(uTh, 0, PC, 0, lane);
        short8 bul = fld(uTl, 0, PC, 0, lane);
        if (wv < 2) {
            oc = mf(buh, bah, mf(buh, bal, mf(bul, bah, oc)));
            const size_t ob = ((size_t)bhi * LSEQ + (size_t)cid * C) * DK;
            *(f32x4*)(Out + ob + (size_t)(r0 + l15) * DK + vcol + quad * 4) = oc;
        }
        {
            f32x4 z = {0.f, 0.f, 0.f, 0.f};
            f32x4 tband = mf(kth, bul, mf(ktl, buh, z));
            accS = mf(kth, buh, accS);
            accS += tband;
            s16x4 h4, l4;
#pragma unroll
            for (int r = 0; r < 4; ++r) {
                unsigned p = split_bf16(accS[r]);
                h4[r] = (short)(p >> 16); l4[r] = (short)(p & 0xffffu);
            }
            *(s16x4*)(STh + l15 * PS + dk0 + quad * 4) = h4;   // S^T[dv][dk]
            *(s16x4*)(STl + l15 * PS + dk0 + quad * 4) = l4;
        }
        __syncthreads();   // end: ST visible; next buffer fully staged
    }

    // final state: Sout[bh][dk][dv]
#pragma unroll
    for (int r = 0; r < 4; ++r)
        Sout[(size_t)bhi * DK * DV + (size_t)(dk0 + quad * 4 + r) * DV + vcol + l15] = accS[r];
}

extern "C" void kernel_launch(void* const* d_in, const int* in_sizes, int n_in,
                              void* d_out, int out_size, void* d_ws, size_t ws_size,
                              hipStream_t stream) {
    const float* Q    = (const float*)d_in[0];
    const float* K    = (const float*)d_in[1];
    const float* V    = (const float*)d_in[2];
    const float* Beta = (const float*)d_in[3];

    float* Out  = (float*)d_out;
    float* Sout = Out + (size_t)BH * LSEQ * DV;

    short* RECg = (short*)d_ws;                                  // 88 MiB records
    float* Uws  = (float*)(RECg + (size_t)BH * NCH * RECSZ);     // +32 MiB

    hipLaunchKernelGGL(k_prep, dim3(BH * NCH), dim3(256), 0, stream,
                       Q, K, V, Beta, RECg, Uws);
    hipLaunchKernelGGL(k_scan, dim3(BH * NDVB), dim3(512), 0, stream,
                       RECg, Uws, Out, Sout);
}